// Round 1
// baseline (182.052 us; speedup 1.0000x reference)
//
#include <hip/hip_runtime.h>

#define U_RESV 400
#define A_RESV 50
#define NCH 8
#define HID 32
#define IN_CH 24

__device__ __forceinline__ float clamp01(float x) { return fminf(fmaxf(x, 0.0f), 1.0f); }

// Accumulate 8-channel bilerp from 4 texel pointers into feat[0..7]
__device__ __forceinline__ void bilerp8(const float* __restrict__ plane,
                                        int i00, int i10, int i01, int i11,
                                        float w00, float w10, float w01, float w11,
                                        float* feat) {
    const float4* p00 = (const float4*)(plane + (size_t)i00 * NCH);
    const float4* p10 = (const float4*)(plane + (size_t)i10 * NCH);
    const float4* p01 = (const float4*)(plane + (size_t)i01 * NCH);
    const float4* p11 = (const float4*)(plane + (size_t)i11 * NCH);
    float4 a0 = p00[0], a1 = p00[1];
    float4 b0 = p10[0], b1 = p10[1];
    float4 c0 = p01[0], c1 = p01[1];
    float4 d0 = p11[0], d1 = p11[1];
    const float* a = (const float*)&a0;  // a0,a1 contiguous? not guaranteed; handle explicitly
    (void)a;
    float av[8] = {a0.x, a0.y, a0.z, a0.w, a1.x, a1.y, a1.z, a1.w};
    float bv[8] = {b0.x, b0.y, b0.z, b0.w, b1.x, b1.y, b1.z, b1.w};
    float cv[8] = {c0.x, c0.y, c0.z, c0.w, c1.x, c1.y, c1.z, c1.w};
    float dv[8] = {d0.x, d0.y, d0.z, d0.w, d1.x, d1.y, d1.z, d1.w};
#pragma unroll
    for (int c = 0; c < 8; ++c) {
        float r = av[c] * w00;
        r = fmaf(bv[c], w10, r);
        r = fmaf(cv[c], w01, r);
        r = fmaf(dv[c], w11, r);
        feat[c] = r;
    }
}

__global__ __launch_bounds__(256) void tpmlp_kernel(
    const float* __restrict__ x,
    const float* __restrict__ u_plane,
    const float* __restrict__ h_plane,
    const float* __restrict__ d_plane,
    const float* __restrict__ W0,
    const float* __restrict__ W1,
    const float* __restrict__ W2,
    const float* __restrict__ W3,
    float* __restrict__ out,
    int n) {
    int t = blockIdx.x * blockDim.x + threadIdx.x;
    if (t >= n) return;

    const float2* xp = (const float2*)(x + (size_t)t * 6);
    float2 p01v = xp[0];   // x0, x1
    float2 p23v = xp[1];   // x2, x3
    float2 p45v = xp[2];   // x4, x5

    float feat[IN_CH];

    // ---- U plane: clamp bilerp, uv = (x0, x1), 400x400 ----
    {
        float u = clamp01(p01v.x) * (float)(U_RESV - 1);
        float v = clamp01(p01v.y) * (float)(U_RESV - 1);
        float x0f = floorf(u), y0f = floorf(v);
        int x0 = (int)x0f, y0 = (int)y0f;
        int x1 = min(x0 + 1, U_RESV - 1);
        int y1 = min(y0 + 1, U_RESV - 1);
        float ur = u - x0f, vr = v - y0f;
        float w00 = (1.0f - ur) * (1.0f - vr);
        float w10 = ur * (1.0f - vr);
        float w01 = (1.0f - ur) * vr;
        float w11 = ur * vr;
        bilerp8(u_plane, y0 * U_RESV + x0, y0 * U_RESV + x1,
                y1 * U_RESV + x0, y1 * U_RESV + x1,
                w00, w10, w01, w11, feat + 0);
    }

    // ---- H plane: wrap-u bilerp, uv = (x3, x2), 50x50 ----
    {
        float uu = p23v.y;                    // x[:,3]
        float vv = p23v.x;                    // x[:,2]
        float uf = uu - floorf(uu);           // % 1.0 (inputs >= 0)
        float u = uf * (float)A_RESV;
        float v = clamp01(vv) * (float)(A_RESV - 1);
        float x0f = floorf(u), y0f = floorf(v);
        int x0 = (int)x0f % A_RESV;
        int x1 = x0 + 1; if (x1 == A_RESV) x1 = 0;
        int y0 = (int)y0f;
        int y1 = min(y0 + 1, A_RESV - 1);
        float ur = u - x0f, vr = v - y0f;
        float w00 = (1.0f - ur) * (1.0f - vr);
        float w10 = ur * (1.0f - vr);
        float w01 = (1.0f - ur) * vr;
        float w11 = ur * vr;
        bilerp8(h_plane, y0 * A_RESV + x0, y0 * A_RESV + x1,
                y1 * A_RESV + x0, y1 * A_RESV + x1,
                w00, w10, w01, w11, feat + 8);
    }

    // ---- D plane: wrap-u bilerp, uv = (x5, x4), 50x50 ----
    {
        float uu = p45v.y;                    // x[:,5]
        float vv = p45v.x;                    // x[:,4]
        float uf = uu - floorf(uu);
        float u = uf * (float)A_RESV;
        float v = clamp01(vv) * (float)(A_RESV - 1);
        float x0f = floorf(u), y0f = floorf(v);
        int x0 = (int)x0f % A_RESV;
        int x1 = x0 + 1; if (x1 == A_RESV) x1 = 0;
        int y0 = (int)y0f;
        int y1 = min(y0 + 1, A_RESV - 1);
        float ur = u - x0f, vr = v - y0f;
        float w00 = (1.0f - ur) * (1.0f - vr);
        float w10 = ur * (1.0f - vr);
        float w01 = (1.0f - ur) * vr;
        float w11 = ur * vr;
        bilerp8(d_plane, y0 * A_RESV + x0, y0 * A_RESV + x1,
                y1 * A_RESV + x0, y1 * A_RESV + x1,
                w00, w10, w01, w11, feat + 16);
    }

    // ---- MLP: 24 -> 32 -> 32 -> 32 -> 3, relu between, no bias ----
    float h0[HID];
#pragma unroll
    for (int o = 0; o < HID; ++o) {
        float acc = 0.0f;
#pragma unroll
        for (int i = 0; i < IN_CH; ++i) acc = fmaf(feat[i], W0[o * IN_CH + i], acc);
        h0[o] = fmaxf(acc, 0.0f);
    }
    float h1[HID];
#pragma unroll
    for (int o = 0; o < HID; ++o) {
        float acc = 0.0f;
#pragma unroll
        for (int i = 0; i < HID; ++i) acc = fmaf(h0[i], W1[o * HID + i], acc);
        h1[o] = fmaxf(acc, 0.0f);
    }
#pragma unroll
    for (int o = 0; o < HID; ++o) {
        float acc = 0.0f;
#pragma unroll
        for (int i = 0; i < HID; ++i) acc = fmaf(h1[i], W2[o * HID + i], acc);
        h0[o] = fmaxf(acc, 0.0f);   // reuse h0 as layer-2 output
    }
#pragma unroll
    for (int o = 0; o < 3; ++o) {
        float acc = 0.0f;
#pragma unroll
        for (int i = 0; i < HID; ++i) acc = fmaf(h0[i], W3[o * HID + i], acc);
        out[(size_t)t * 3 + o] = acc;
    }
}

extern "C" void kernel_launch(void* const* d_in, const int* in_sizes, int n_in,
                              void* d_out, int out_size, void* d_ws, size_t ws_size,
                              hipStream_t stream) {
    const float* x       = (const float*)d_in[0];
    const float* u_plane = (const float*)d_in[1];
    const float* h_plane = (const float*)d_in[2];
    const float* d_plane = (const float*)d_in[3];
    const float* W0      = (const float*)d_in[4];
    const float* W1      = (const float*)d_in[5];
    const float* W2      = (const float*)d_in[6];
    const float* W3      = (const float*)d_in[7];
    float* out = (float*)d_out;

    int n = in_sizes[0] / 6;
    int block = 256;
    int grid = (n + block - 1) / block;
    tpmlp_kernel<<<grid, block, 0, stream>>>(x, u_plane, h_plane, d_plane,
                                             W0, W1, W2, W3, out, n);
}

// Round 4
// 145.845 us; speedup vs baseline: 1.2483x; 1.2483x over previous
//
#include <hip/hip_runtime.h>

typedef _Float16 half4 __attribute__((ext_vector_type(4)));
typedef _Float16 half8 __attribute__((ext_vector_type(8)));
typedef float floatx4 __attribute__((ext_vector_type(4)));

#define U_RESV 400
#define A_RESV 50

__device__ __forceinline__ float clamp01(float x) { return fminf(fmaxf(x, 0.0f), 1.0f); }

__device__ __forceinline__ floatx4 mfma16(half4 a, half4 b, floatx4 c) {
    return __builtin_amdgcn_mfma_f32_16x16x16f16(a, b, c, 0, 0, 0);
}

__device__ __forceinline__ half4 cvt4(const float* __restrict__ p) {
    float4 v = *(const float4*)p;
    half4 h;
    h[0] = (_Float16)v.x; h[1] = (_Float16)v.y;
    h[2] = (_Float16)v.z; h[3] = (_Float16)v.w;
    return h;
}
__device__ __forceinline__ half4 zero4() {
    half4 h; h[0] = h[1] = h[2] = h[3] = (_Float16)0.f; return h;
}

__device__ __forceinline__ void bilerp8(const float* __restrict__ plane,
                                        int i00, int i10, int i01, int i11,
                                        float w00, float w10, float w01, float w11,
                                        float* feat) {
    const float4* p00 = (const float4*)(plane + (size_t)i00 * 8);
    const float4* p10 = (const float4*)(plane + (size_t)i10 * 8);
    const float4* p01 = (const float4*)(plane + (size_t)i01 * 8);
    const float4* p11 = (const float4*)(plane + (size_t)i11 * 8);
    float4 a0 = p00[0], a1 = p00[1];
    float4 b0 = p10[0], b1 = p10[1];
    float4 c0 = p01[0], c1 = p01[1];
    float4 d0 = p11[0], d1 = p11[1];
    float av[8] = {a0.x, a0.y, a0.z, a0.w, a1.x, a1.y, a1.z, a1.w};
    float bv[8] = {b0.x, b0.y, b0.z, b0.w, b1.x, b1.y, b1.z, b1.w};
    float cv[8] = {c0.x, c0.y, c0.z, c0.w, c1.x, c1.y, c1.z, c1.w};
    float dv[8] = {d0.x, d0.y, d0.z, d0.w, d1.x, d1.y, d1.z, d1.w};
#pragma unroll
    for (int c = 0; c < 8; ++c) {
        float r = av[c] * w00;
        r = fmaf(bv[c], w10, r);
        r = fmaf(cv[c], w01, r);
        r = fmaf(dv[c], w11, r);
        feat[c] = r;
    }
}

// Classic 16x16x16 f16 MFMA maps (CDNA lab-notes, stable since gfx908;
// B-map independently confirmed by m162 tr_b16, D-map by m89 shape-determined):
//   A: lane 16q+c holds A[row=c][k=4q+e], e=0..3
//   B: lane 16q+c holds B[k=4q+e][col=c]
//   D: lane 16q+c reg r holds D[row=4q+r][col=c]
// Chain identity: D reg r of lane L == next-layer B element e=r of lane L
// (k-half m of next layer comes from the m-th row-tile's D). So the MLP
// chains fully in registers; LDS used only once to stage feat.

__global__ __launch_bounds__(256) void tpmlp_kernel(
    const float* __restrict__ x,
    const float* __restrict__ u_plane,
    const float* __restrict__ h_plane,
    const float* __restrict__ d_plane,
    const float* __restrict__ W0,
    const float* __restrict__ W1,
    const float* __restrict__ W2,
    const float* __restrict__ W3,
    float* __restrict__ out) {
    const int tid  = threadIdx.x;
    const int lane = tid & 63;
    const int wv   = tid >> 6;
    const int q    = lane >> 4;   // k-group
    const int c15  = lane & 15;   // row/col within 16-tile

    // 4 waves x 64 points x (32 ch + 8 pad) f16 ; row stride 80 B (16-aligned)
    __shared__ _Float16 flds[4][64][40];

    // ---- W fragments (f16) in registers ----
    // wXf[m][h]: A-tile rows 16m.., k-half h (k = 16h + 4q + e)
    half4 w0f[2][2], w1f[2][2], w2f[2][2], w3f[2];
#pragma unroll
    for (int m = 0; m < 2; ++m) {
        w0f[m][0] = cvt4(W0 + (size_t)(16 * m + c15) * 24 + 4 * q);           // ch 4q..4q+3 (<16, valid)
        w0f[m][1] = (q < 2) ? cvt4(W0 + (size_t)(16 * m + c15) * 24 + 16 + 4 * q)
                            : zero4();                                        // ch 16+4q.. ; >=24 zero
        w1f[m][0] = cvt4(W1 + (size_t)(16 * m + c15) * 32 + 4 * q);
        w1f[m][1] = cvt4(W1 + (size_t)(16 * m + c15) * 32 + 16 + 4 * q);
        w2f[m][0] = cvt4(W2 + (size_t)(16 * m + c15) * 32 + 4 * q);
        w2f[m][1] = cvt4(W2 + (size_t)(16 * m + c15) * 32 + 16 + 4 * q);
    }
    w3f[0] = (c15 < 3) ? cvt4(W3 + (size_t)c15 * 32 + 4 * q) : zero4();       // 3x32 padded to 16 rows
    w3f[1] = (c15 < 3) ? cvt4(W3 + (size_t)c15 * 32 + 16 + 4 * q) : zero4();

    // ---- gather features (verified round-1 code) ----
    const size_t t = (size_t)blockIdx.x * 256 + tid;
    const float2* xp = (const float2*)(x + t * 6);
    float2 p01v = xp[0];
    float2 p23v = xp[1];
    float2 p45v = xp[2];

    float feat[24];
    {
        float u = clamp01(p01v.x) * (float)(U_RESV - 1);
        float v = clamp01(p01v.y) * (float)(U_RESV - 1);
        float x0f = floorf(u), y0f = floorf(v);
        int x0 = (int)x0f, y0 = (int)y0f;
        int x1 = min(x0 + 1, U_RESV - 1);
        int y1 = min(y0 + 1, U_RESV - 1);
        float ur = u - x0f, vr = v - y0f;
        float w00 = (1.0f - ur) * (1.0f - vr);
        float w10 = ur * (1.0f - vr);
        float w01 = (1.0f - ur) * vr;
        float w11 = ur * vr;
        bilerp8(u_plane, y0 * U_RESV + x0, y0 * U_RESV + x1,
                y1 * U_RESV + x0, y1 * U_RESV + x1, w00, w10, w01, w11, feat + 0);
    }
    {
        float uu = p23v.y, vv = p23v.x;
        float uf = uu - floorf(uu);
        float u = uf * (float)A_RESV;
        float v = clamp01(vv) * (float)(A_RESV - 1);
        float x0f = floorf(u), y0f = floorf(v);
        int x0 = (int)x0f % A_RESV;
        int x1 = x0 + 1; if (x1 == A_RESV) x1 = 0;
        int y0 = (int)y0f;
        int y1 = min(y0 + 1, A_RESV - 1);
        float ur = u - x0f, vr = v - y0f;
        float w00 = (1.0f - ur) * (1.0f - vr);
        float w10 = ur * (1.0f - vr);
        float w01 = (1.0f - ur) * vr;
        float w11 = ur * vr;
        bilerp8(h_plane, y0 * A_RESV + x0, y0 * A_RESV + x1,
                y1 * A_RESV + x0, y1 * A_RESV + x1, w00, w10, w01, w11, feat + 8);
    }
    {
        float uu = p45v.y, vv = p45v.x;
        float uf = uu - floorf(uu);
        float u = uf * (float)A_RESV;
        float v = clamp01(vv) * (float)(A_RESV - 1);
        float x0f = floorf(u), y0f = floorf(v);
        int x0 = (int)x0f % A_RESV;
        int x1 = x0 + 1; if (x1 == A_RESV) x1 = 0;
        int y0 = (int)y0f;
        int y1 = min(y0 + 1, A_RESV - 1);
        float ur = u - x0f, vr = v - y0f;
        float w00 = (1.0f - ur) * (1.0f - vr);
        float w10 = ur * (1.0f - vr);
        float w01 = (1.0f - ur) * vr;
        float w11 = ur * vr;
        bilerp8(d_plane, y0 * A_RESV + x0, y0 * A_RESV + x1,
                y1 * A_RESV + x0, y1 * A_RESV + x1, w00, w10, w01, w11, feat + 16);
    }

    // ---- stage feat (f16) to LDS: row = my point, ch 0..23 + zero pad 24..31 ----
    {
        _Float16* myrow = &flds[wv][lane][0];
#pragma unroll
        for (int kb = 0; kb < 3; ++kb) {
            half8 h;
#pragma unroll
            for (int i = 0; i < 8; ++i) h[i] = (_Float16)feat[kb * 8 + i];
            *(half8*)(myrow + kb * 8) = h;
        }
        half8 z;
#pragma unroll
        for (int i = 0; i < 8; ++i) z[i] = (_Float16)0.f;
        *(half8*)(myrow + 24) = z;
    }
    __syncthreads();

    floatx4 zf; zf[0] = 0.f; zf[1] = 0.f; zf[2] = 0.f; zf[3] = 0.f;

    // ---- layer 0: B from LDS (k-half h -> ch 16h+4q+e of point 16j+c15) ----
    half4 b0[4], b1[4];
    {
        const _Float16* wb = &flds[wv][0][0];
#pragma unroll
        for (int j = 0; j < 4; ++j) {
            b0[j] = *(const half4*)(wb + (size_t)(16 * j + c15) * 40 + 4 * q);
            b1[j] = *(const half4*)(wb + (size_t)(16 * j + c15) * 40 + 16 + 4 * q);
        }
    }

    floatx4 cc[2][4];
#pragma unroll
    for (int m = 0; m < 2; ++m)
#pragma unroll
        for (int j = 0; j < 4; ++j)
            cc[m][j] = mfma16(w0f[m][1], b1[j], mfma16(w0f[m][0], b0[j], zf));

    // relu + cvt -> next B (in-register chain: reg r == element e)
#pragma unroll
    for (int j = 0; j < 4; ++j)
#pragma unroll
        for (int e = 0; e < 4; ++e) {
            b0[j][e] = (_Float16)fmaxf(cc[0][j][e], 0.f);
            b1[j][e] = (_Float16)fmaxf(cc[1][j][e], 0.f);
        }

    // ---- layer 1 ----
#pragma unroll
    for (int m = 0; m < 2; ++m)
#pragma unroll
        for (int j = 0; j < 4; ++j)
            cc[m][j] = mfma16(w1f[m][1], b1[j], mfma16(w1f[m][0], b0[j], zf));
#pragma unroll
    for (int j = 0; j < 4; ++j)
#pragma unroll
        for (int e = 0; e < 4; ++e) {
            b0[j][e] = (_Float16)fmaxf(cc[0][j][e], 0.f);
            b1[j][e] = (_Float16)fmaxf(cc[1][j][e], 0.f);
        }

    // ---- layer 2 ----
#pragma unroll
    for (int m = 0; m < 2; ++m)
#pragma unroll
        for (int j = 0; j < 4; ++j)
            cc[m][j] = mfma16(w2f[m][1], b1[j], mfma16(w2f[m][0], b0[j], zf));
#pragma unroll
    for (int j = 0; j < 4; ++j)
#pragma unroll
        for (int e = 0; e < 4; ++e) {
            b0[j][e] = (_Float16)fmaxf(cc[0][j][e], 0.f);
            b1[j][e] = (_Float16)fmaxf(cc[1][j][e], 0.f);
        }

    // ---- layer 3: rows 0..2 valid ----
    floatx4 c3[4];
#pragma unroll
    for (int j = 0; j < 4; ++j)
        c3[j] = mfma16(w3f[1], b1[j], mfma16(w3f[0], b0[j], zf));

    // lanes 0..15 (q=0) hold D rows 0..3 = out channels 0..2 in regs 0..2
    if (lane < 16) {
        const size_t base = (size_t)blockIdx.x * 256 + (size_t)wv * 64;
#pragma unroll
        for (int j = 0; j < 4; ++j) {
            size_t p = base + (size_t)j * 16 + lane;
            float* o = out + p * 3;
            o[0] = c3[j][0];
            o[1] = c3[j][1];
            o[2] = c3[j][2];
        }
    }
}

extern "C" void kernel_launch(void* const* d_in, const int* in_sizes, int n_in,
                              void* d_out, int out_size, void* d_ws, size_t ws_size,
                              hipStream_t stream) {
    const float* x       = (const float*)d_in[0];
    const float* u_plane = (const float*)d_in[1];
    const float* h_plane = (const float*)d_in[2];
    const float* d_plane = (const float*)d_in[3];
    const float* W0      = (const float*)d_in[4];
    const float* W1      = (const float*)d_in[5];
    const float* W2      = (const float*)d_in[6];
    const float* W3      = (const float*)d_in[7];
    float* out = (float*)d_out;

    int n = in_sizes[0] / 6;          // 2^21, divisible by 256
    int block = 256;
    int grid = n / block;
    tpmlp_kernel<<<grid, block, 0, stream>>>(x, u_plane, h_plane, d_plane,
                                             W0, W1, W2, W3, out);
}

// Round 5
// 93.589 us; speedup vs baseline: 1.9452x; 1.5584x over previous
//
#include <hip/hip_runtime.h>

typedef _Float16 half4 __attribute__((ext_vector_type(4)));
typedef float floatx4 __attribute__((ext_vector_type(4)));

#define U_RESV 400
#define A_RESV 50

__device__ __forceinline__ float clamp01(float x) { return fminf(fmaxf(x, 0.0f), 1.0f); }

__device__ __forceinline__ floatx4 mfma16(half4 a, half4 b, floatx4 c) {
    return __builtin_amdgcn_mfma_f32_16x16x16f16(a, b, c, 0, 0, 0);
}
__device__ __forceinline__ half4 zero4() {
    half4 h; h[0] = h[1] = h[2] = h[3] = (_Float16)0.f; return h;
}

// Two lanes per point: even lane = texel ch 0-3, odd lane = ch 4-7.
// Pair's two 16B loads share one 64B line -> TA coalesces -> 1 transaction/texel.
// MFMA maps (verified in R4, 16x16x16 f16):
//   A: lane 16q+c holds A[row=c][k=4q+e];  B: lane 16q+c holds B[k=4q+e][col=c]
//   D: lane 16q+c reg r holds D[row=4q+r][col=c]
// Chain identity: D reg r == next-layer B elem e (m-tile -> k-half). In-register MLP chain.

__global__ __launch_bounds__(256, 5) void tpmlp_kernel(
    const float* __restrict__ x,
    const float* __restrict__ u_plane,
    const float* __restrict__ h_plane,
    const float* __restrict__ d_plane,
    const float* __restrict__ W0,
    const float* __restrict__ W1,
    const float* __restrict__ W2,
    const float* __restrict__ W3,
    float* __restrict__ out) {
    const int tid  = threadIdx.x;
    const int lane = tid & 63;
    const int wv   = tid >> 6;
    const int hf   = lane & 1;                 // channel half (0: ch0-3, 1: ch4-7)
    const int pidx = wv * 32 + (lane >> 1);    // point within block (0..127)
    const int q    = lane >> 4;                // MFMA k-group
    const int c15  = lane & 15;

    // feat: 128 points x 28 halves (24 used), row stride 56 B (14 banks -> <=2-way)
    __shared__ __align__(16) _Float16 fl[128 * 28];
    __shared__ __align__(16) _Float16 w0l[32 * 24];   // stride 24 (48 B)
    __shared__ __align__(16) _Float16 w1l[32 * 36];   // stride 36 (72 B, conflict-free)
    __shared__ __align__(16) _Float16 w2l[32 * 36];
    __shared__ __align__(16) _Float16 w3l[16 * 36];   // rows 3..15 zero

    // ---- x load + gather addresses + issue all 12 texel loads ----
    const size_t P = (size_t)blockIdx.x * 128 + pidx;
    const float2* xp = (const float2*)(x + P * 6);
    float2 p01v = xp[0], p23v = xp[1], p45v = xp[2];

    int oU0, oU1, oU2, oU3;  float uw00, uw10, uw01, uw11;
    {
        float u = clamp01(p01v.x) * (float)(U_RESV - 1);
        float v = clamp01(p01v.y) * (float)(U_RESV - 1);
        float x0f = floorf(u), y0f = floorf(v);
        int x0 = (int)x0f, y0 = (int)y0f;
        int x1 = min(x0 + 1, U_RESV - 1), y1 = min(y0 + 1, U_RESV - 1);
        float ur = u - x0f, vr = v - y0f;
        uw00 = (1.0f - ur) * (1.0f - vr); uw10 = ur * (1.0f - vr);
        uw01 = (1.0f - ur) * vr;          uw11 = ur * vr;
        oU0 = (y0 * U_RESV + x0) * 8 + hf * 4;
        oU1 = (y0 * U_RESV + x1) * 8 + hf * 4;
        oU2 = (y1 * U_RESV + x0) * 8 + hf * 4;
        oU3 = (y1 * U_RESV + x1) * 8 + hf * 4;
    }
    int oH0, oH1, oH2, oH3;  float hw00, hw10, hw01, hw11;
    {
        float uu = p23v.y, vv = p23v.x;
        float uf = uu - floorf(uu);
        float u = uf * (float)A_RESV;
        float v = clamp01(vv) * (float)(A_RESV - 1);
        float x0f = floorf(u), y0f = floorf(v);
        int x0 = (int)x0f % A_RESV;
        int x1 = x0 + 1; if (x1 == A_RESV) x1 = 0;
        int y0 = (int)y0f;
        int y1 = min(y0 + 1, A_RESV - 1);
        float ur = u - x0f, vr = v - y0f;
        hw00 = (1.0f - ur) * (1.0f - vr); hw10 = ur * (1.0f - vr);
        hw01 = (1.0f - ur) * vr;          hw11 = ur * vr;
        oH0 = (y0 * A_RESV + x0) * 8 + hf * 4;
        oH1 = (y0 * A_RESV + x1) * 8 + hf * 4;
        oH2 = (y1 * A_RESV + x0) * 8 + hf * 4;
        oH3 = (y1 * A_RESV + x1) * 8 + hf * 4;
    }
    int oD0, oD1, oD2, oD3;  float dw00, dw10, dw01, dw11;
    {
        float uu = p45v.y, vv = p45v.x;
        float uf = uu - floorf(uu);
        float u = uf * (float)A_RESV;
        float v = clamp01(vv) * (float)(A_RESV - 1);
        float x0f = floorf(u), y0f = floorf(v);
        int x0 = (int)x0f % A_RESV;
        int x1 = x0 + 1; if (x1 == A_RESV) x1 = 0;
        int y0 = (int)y0f;
        int y1 = min(y0 + 1, A_RESV - 1);
        float ur = u - x0f, vr = v - y0f;
        dw00 = (1.0f - ur) * (1.0f - vr); dw10 = ur * (1.0f - vr);
        dw01 = (1.0f - ur) * vr;          dw11 = ur * vr;
        oD0 = (y0 * A_RESV + x0) * 8 + hf * 4;
        oD1 = (y0 * A_RESV + x1) * 8 + hf * 4;
        oD2 = (y1 * A_RESV + x0) * 8 + hf * 4;
        oD3 = (y1 * A_RESV + x1) * 8 + hf * 4;
    }

    // issue all 12 independent 16B loads
    const float4 tU0 = *(const float4*)(u_plane + oU0);
    const float4 tU1 = *(const float4*)(u_plane + oU1);
    const float4 tU2 = *(const float4*)(u_plane + oU2);
    const float4 tU3 = *(const float4*)(u_plane + oU3);
    const float4 tH0 = *(const float4*)(h_plane + oH0);
    const float4 tH1 = *(const float4*)(h_plane + oH1);
    const float4 tH2 = *(const float4*)(h_plane + oH2);
    const float4 tH3 = *(const float4*)(h_plane + oH3);
    const float4 tD0 = *(const float4*)(d_plane + oD0);
    const float4 tD1 = *(const float4*)(d_plane + oD1);
    const float4 tD2 = *(const float4*)(d_plane + oD2);
    const float4 tD3 = *(const float4*)(d_plane + oD3);

    // ---- stage weights to LDS (overlaps texel-load latency) ----
    for (int i = tid; i < 32 * 24; i += 256) w0l[i] = (_Float16)W0[i];
    for (int i = tid; i < 32 * 32; i += 256) {
        int r = i >> 5, c = i & 31;
        w1l[r * 36 + c] = (_Float16)W1[i];
        w2l[r * 36 + c] = (_Float16)W2[i];
    }
    for (int i = tid; i < 16 * 36; i += 256) {
        int r = i / 36, c = i - r * 36;
        w3l[i] = (r < 3 && c < 32) ? (_Float16)W3[r * 32 + c] : (_Float16)0.f;
    }

    // ---- weighted sums (exact R1/R4 per-channel FMA order) ----
    float fU[4], fH[4], fD[4];
    {
        const float* a = (const float*)&tU0; const float* b = (const float*)&tU1;
        const float* c = (const float*)&tU2; const float* d = (const float*)&tU3;
#pragma unroll
        for (int i = 0; i < 4; ++i) {
            float r = a[i] * uw00;
            r = fmaf(b[i], uw10, r);
            r = fmaf(c[i], uw01, r);
            r = fmaf(d[i], uw11, r);
            fU[i] = r;
        }
    }
    {
        const float* a = (const float*)&tH0; const float* b = (const float*)&tH1;
        const float* c = (const float*)&tH2; const float* d = (const float*)&tH3;
#pragma unroll
        for (int i = 0; i < 4; ++i) {
            float r = a[i] * hw00;
            r = fmaf(b[i], hw10, r);
            r = fmaf(c[i], hw01, r);
            r = fmaf(d[i], hw11, r);
            fH[i] = r;
        }
    }
    {
        const float* a = (const float*)&tD0; const float* b = (const float*)&tD1;
        const float* c = (const float*)&tD2; const float* d = (const float*)&tD3;
#pragma unroll
        for (int i = 0; i < 4; ++i) {
            float r = a[i] * dw00;
            r = fmaf(b[i], dw10, r);
            r = fmaf(c[i], dw01, r);
            r = fmaf(d[i], dw11, r);
            fD[i] = r;
        }
    }

    // ---- feat -> f16 -> LDS ----
    {
        _Float16* row = fl + pidx * 28;
        half4 hU, hH, hD;
#pragma unroll
        for (int i = 0; i < 4; ++i) {
            hU[i] = (_Float16)fU[i];
            hH[i] = (_Float16)fH[i];
            hD[i] = (_Float16)fD[i];
        }
        *(half4*)(row + hf * 4)      = hU;   // ch 0-7   (plane U)
        *(half4*)(row + 8 + hf * 4)  = hH;   // ch 8-15  (plane H)
        *(half4*)(row + 16 + hf * 4) = hD;   // ch 16-23 (plane D)
    }
    __syncthreads();

    // ---- MLP: wave owns 32 points, j-tiles {0,1} ----
    floatx4 zf; zf[0] = 0.f; zf[1] = 0.f; zf[2] = 0.f; zf[3] = 0.f;
    const _Float16* wb = fl + (size_t)wv * 32 * 28;

    half4 b0[2], b1[2];
#pragma unroll
    for (int j = 0; j < 2; ++j) {
        const _Float16* r = wb + (size_t)(j * 16 + c15) * 28;
        b0[j] = *(const half4*)(r + q * 4);
        b1[j] = (q < 2) ? *(const half4*)(r + 16 + q * 4) : zero4();  // ch 24-31 zero
    }

    floatx4 cc[2][2];
    // layer 0 (K=24: k-half1 zero for q>=2 on both operands)
#pragma unroll
    for (int m = 0; m < 2; ++m) {
        half4 a0 = *(const half4*)(w0l + (size_t)(16 * m + c15) * 24 + q * 4);
        half4 a1 = (q < 2) ? *(const half4*)(w0l + (size_t)(16 * m + c15) * 24 + 16 + q * 4) : zero4();
#pragma unroll
        for (int j = 0; j < 2; ++j)
            cc[m][j] = mfma16(a1, b1[j], mfma16(a0, b0[j], zf));
    }
#pragma unroll
    for (int j = 0; j < 2; ++j)
#pragma unroll
        for (int e = 0; e < 4; ++e) {
            b0[j][e] = (_Float16)fmaxf(cc[0][j][e], 0.f);
            b1[j][e] = (_Float16)fmaxf(cc[1][j][e], 0.f);
        }

    // layer 1
#pragma unroll
    for (int m = 0; m < 2; ++m) {
        half4 a0 = *(const half4*)(w1l + (size_t)(16 * m + c15) * 36 + q * 4);
        half4 a1 = *(const half4*)(w1l + (size_t)(16 * m + c15) * 36 + 16 + q * 4);
#pragma unroll
        for (int j = 0; j < 2; ++j)
            cc[m][j] = mfma16(a1, b1[j], mfma16(a0, b0[j], zf));
    }
#pragma unroll
    for (int j = 0; j < 2; ++j)
#pragma unroll
        for (int e = 0; e < 4; ++e) {
            b0[j][e] = (_Float16)fmaxf(cc[0][j][e], 0.f);
            b1[j][e] = (_Float16)fmaxf(cc[1][j][e], 0.f);
        }

    // layer 2
#pragma unroll
    for (int m = 0; m < 2; ++m) {
        half4 a0 = *(const half4*)(w2l + (size_t)(16 * m + c15) * 36 + q * 4);
        half4 a1 = *(const half4*)(w2l + (size_t)(16 * m + c15) * 36 + 16 + q * 4);
#pragma unroll
        for (int j = 0; j < 2; ++j)
            cc[m][j] = mfma16(a1, b1[j], mfma16(a0, b0[j], zf));
    }
#pragma unroll
    for (int j = 0; j < 2; ++j)
#pragma unroll
        for (int e = 0; e < 4; ++e) {
            b0[j][e] = (_Float16)fmaxf(cc[0][j][e], 0.f);
            b1[j][e] = (_Float16)fmaxf(cc[1][j][e], 0.f);
        }

    // layer 3 (rows 0-2 valid; w3l rows 3-15 staged as zeros)
    floatx4 c3[2];
    {
        half4 a0 = *(const half4*)(w3l + (size_t)c15 * 36 + q * 4);
        half4 a1 = *(const half4*)(w3l + (size_t)c15 * 36 + 16 + q * 4);
#pragma unroll
        for (int j = 0; j < 2; ++j)
            c3[j] = mfma16(a1, b1[j], mfma16(a0, b0[j], zf));
    }

    if (lane < 16) {
        const size_t base = (size_t)blockIdx.x * 128 + (size_t)wv * 32;
#pragma unroll
        for (int j = 0; j < 2; ++j) {
            size_t p = base + (size_t)j * 16 + lane;
            float* o = out + p * 3;
            o[0] = c3[j][0];
            o[1] = c3[j][1];
            o[2] = c3[j][2];
        }
    }
}

extern "C" void kernel_launch(void* const* d_in, const int* in_sizes, int n_in,
                              void* d_out, int out_size, void* d_ws, size_t ws_size,
                              hipStream_t stream) {
    const float* x       = (const float*)d_in[0];
    const float* u_plane = (const float*)d_in[1];
    const float* h_plane = (const float*)d_in[2];
    const float* d_plane = (const float*)d_in[3];
    const float* W0      = (const float*)d_in[4];
    const float* W1      = (const float*)d_in[5];
    const float* W2      = (const float*)d_in[6];
    const float* W3      = (const float*)d_in[7];
    float* out = (float*)d_out;

    int n = in_sizes[0] / 6;          // 2^21
    int block = 256;
    int grid = n / 128;               // 128 points per block (2 lanes/point)
    tpmlp_kernel<<<grid, block, 0, stream>>>(x, u_plane, h_plane, d_plane,
                                             W0, W1, W2, W3, out);
}